// Round 2
// baseline (569.305 us; speedup 1.0000x reference)
//
#include <hip/hip_runtime.h>

// Fern patch-descriptor pipeline, fully fused single kernel.
//   x:(64,8,128,128) f32, thresholds:(8,12) f32, table:(8,4096,32) f32,
//   chan_idx:(8,12,2) i32, offsets:(8,12,2,2) i32
//   out:(64, 32*114*114) f32
//
// Tile design: output tile 19x19 (114 = 6*19 exact), positions tile 25x25,
// x tile 8ch x 33x33.  LDS = 34848B (x) + 90000B (votes, stride 36 floats)
// = 124848B -> 1 block/CU.  640 threads (10 waves): 625 positions in ONE
// balanced pass (R0 used 512 -> 2 ragged passes).
// Phase 2 restructured: all words/confs first (independent exp trees), then
// all 64 table gathers pipelined (R0 serialized 8x ~200cyc L2 stalls).

#define NN 64
#define CC 8
#define HH 128
#define WW 128
#define MM 8
#define KK 12
#define DD 32
#define OUTS 114
#define TT 19          // output tile edge
#define PT 25          // position tile edge = TT + POOL - 1
#define XT 33          // x tile edge = PT + L - 1
#define XSTRIDE (XT*XT)   // 1089
#define VSTRIDE 36        // vote row stride (pad 32 -> 36, 16B-aligned rows)
#define NPOSI (PT*PT)     // 625
#define THREADS 640
#define POOLW 7

#define LDS_FLOATS (CC*XSTRIDE + NPOSI*VSTRIDE)   // 8712 + 22500 = 31212
#define LDS_BYTES  (LDS_FLOATS*4)                 // 124848

__global__ __launch_bounds__(THREADS, 1)
void fern_fused(const float* __restrict__ x,
                const float* __restrict__ thresholds,
                const float* __restrict__ table,
                const int*   __restrict__ chan_idx,
                const int*   __restrict__ offsets,
                float* __restrict__ out)
{
    extern __shared__ float smem[];
    float* xs = smem;                    // [8][33][33]
    float* vs = smem + CC*XSTRIDE;       // [625][36]

    const int tile = blockIdx.x;         // 0..2303
    const int n    = tile / 36;
    const int t2   = tile - n*36;
    const int ti   = t2 / 6;
    const int tj   = t2 - ti*6;
    const int i0   = ti * TT;            // 0..95
    const int j0   = tj * TT;

    const int tid = threadIdx.x;

    // ---------------- Phase 1: stage x tile into LDS ----------------
    // rows i0..i0+32 <= 127, cols j0..j0+32 <= 127 exactly: no clamping.
    const float* xn = x + (size_t)n * (CC*HH*WW);
    for (int idx = tid; idx < CC*XSTRIDE; idx += THREADS) {
        int c   = idx / XSTRIDE;
        int rem = idx - c*XSTRIDE;
        int r   = rem / XT;
        int col = rem - r*XT;
        xs[idx] = xn[(c*HH + (i0 + r))*WW + (j0 + col)];
    }
    __syncthreads();

    // ---------------- Phase 2: per-position fern votes into LDS ------------
    // 625 positions, 640 threads: one balanced pass.
    if (tid < NPOSI) {
        const int y  = tid / PT;
        const int j  = tid - y*PT;
        const int pb = y*XT + j;

        // --- all 8 ferns' word+conf first: 96 independent exp chains ---
        unsigned wordv[MM];
        float    confv[MM];
        #pragma unroll
        for (int m = 0; m < MM; ++m) {
            float e[KK];
            unsigned w = 0;
            #pragma unroll
            for (int k = 0; k < KK; ++k) {
                const int mk = m*KK + k;
                // compile-time mk -> wave-uniform scalar loads
                int c1  = chan_idx[mk*2 + 0];
                int c2  = chan_idx[mk*2 + 1];
                int dy1 = offsets[mk*4 + 0];
                int dx1 = offsets[mk*4 + 1];
                int dy2 = offsets[mk*4 + 2];
                int dx2 = offsets[mk*4 + 3];
                float thr = thresholds[mk];
                float p1 = xs[c1*XSTRIDE + dy1*XT + dx1 + pb];
                float p2 = xs[c2*XSTRIDE + dy2*XT + dx2 + pb];
                float z  = (p1 - p2) - thr;
                if (z > 0.f) w |= (1u << k);
                e[k] = __expf(-10.f * fabsf(z));
            }
            // conf = 1 / prod(1+e_k): balanced tree, depth 4 (was 12-deep chain)
            float q0 = (1.f + e[0])  * (1.f + e[1]);
            float q1 = (1.f + e[2])  * (1.f + e[3]);
            float q2 = (1.f + e[4])  * (1.f + e[5]);
            float q3 = (1.f + e[6])  * (1.f + e[7]);
            float q4 = (1.f + e[8])  * (1.f + e[9]);
            float q5 = (1.f + e[10]) * (1.f + e[11]);
            float P  = ((q0*q1) * (q2*q3)) * (q4*q5);
            wordv[m] = w;
            confv[m] = __builtin_amdgcn_rcpf(P);
        }

        // --- gather: 8 row pointers, then 64 loads pipelined ---
        const float4* trow[MM];
        #pragma unroll
        for (int m = 0; m < MM; ++m)
            trow[m] = (const float4*)(table + (((size_t)m << 12) + wordv[m])*DD);

        float4* vrow = (float4*)(vs + tid*VSTRIDE);
        #pragma unroll
        for (int d4 = 0; d4 < DD/4; ++d4) {
            float4 acc = make_float4(0.f, 0.f, 0.f, 0.f);
            #pragma unroll
            for (int m = 0; m < MM; ++m) {
                float4 t = trow[m][d4];     // 8 independent L2 loads per chunk
                float  c = confv[m];
                acc.x += c*t.x; acc.y += c*t.y; acc.z += c*t.z; acc.w += c*t.w;
            }
            vrow[d4] = acc;
        }
    }
    __syncthreads();

    // ---------------- Phase 3a: horizontal 7-window running sums (in-place) --
    // work item = (y, d4): 25*8 = 200 items
    for (int w = tid; w < PT*8; w += THREADS) {
        int y  = w / 8;
        int d4 = w - y*8;
        float4 s = make_float4(0.f, 0.f, 0.f, 0.f);
        float4 ring[POOLW];
        #pragma unroll
        for (int j = 0; j < PT; ++j) {
            float4 v = *(const float4*)(vs + (y*PT + j)*VSTRIDE + d4*4);
            if (j >= POOLW) {
                float4 o = ring[j % POOLW];
                s.x -= o.x; s.y -= o.y; s.z -= o.z; s.w -= o.w;
            }
            ring[j % POOLW] = v;
            s.x += v.x; s.y += v.y; s.z += v.z; s.w += v.w;
            if (j >= POOLW-1) {
                // write index j-6 < j: already consumed, safe in-place
                *(float4*)(vs + (y*PT + (j - POOLW + 1))*VSTRIDE + d4*4) = s;
            }
        }
    }
    __syncthreads();

    // ---------------- Phase 3b: vertical 7-window + store -----------------
    // work item = (d4, jo) with jo fastest for store coalescing: 8*19 = 152
    const float inv = 1.f / 49.f;
    float* outn = out + (size_t)n * (DD*OUTS*OUTS);
    for (int w = tid; w < 8*TT; w += THREADS) {
        int d4 = w / TT;
        int jo = w - d4*TT;
        float4 s = make_float4(0.f, 0.f, 0.f, 0.f);
        float4 ring[POOLW];
        #pragma unroll
        for (int y = 0; y < PT; ++y) {
            float4 v = *(const float4*)(vs + (y*PT + jo)*VSTRIDE + d4*4);
            if (y >= POOLW) {
                float4 o = ring[y % POOLW];
                s.x -= o.x; s.y -= o.y; s.z -= o.z; s.w -= o.w;
            }
            ring[y % POOLW] = v;
            s.x += v.x; s.y += v.y; s.z += v.z; s.w += v.w;
            if (y >= POOLW-1) {
                int io = y - POOLW + 1;
                size_t base = ((size_t)(d4*4)*OUTS + (i0 + io))*OUTS + (j0 + jo);
                outn[base                      ] = s.x * inv;
                outn[base +   (size_t)OUTS*OUTS] = s.y * inv;
                outn[base + 2*(size_t)OUTS*OUTS] = s.z * inv;
                outn[base + 3*(size_t)OUTS*OUTS] = s.w * inv;
            }
        }
    }
}

extern "C" void kernel_launch(void* const* d_in, const int* in_sizes, int n_in,
                              void* d_out, int out_size, void* d_ws, size_t ws_size,
                              hipStream_t stream) {
    const float* x          = (const float*)d_in[0];
    const float* thresholds = (const float*)d_in[1];
    const float* table      = (const float*)d_in[2];
    const int*   chan_idx   = (const int*)d_in[3];
    const int*   offsets    = (const int*)d_in[4];
    float* out = (float*)d_out;

    // dynamic LDS > 64KB needs the opt-in attribute (idempotent, capture-safe)
    hipFuncSetAttribute((const void*)fern_fused,
                        hipFuncAttributeMaxDynamicSharedMemorySize, LDS_BYTES);

    dim3 grid(NN * 36);
    dim3 block(THREADS);
    fern_fused<<<grid, block, LDS_BYTES, stream>>>(x, thresholds, table,
                                                   chan_idx, offsets, out);
}

// Round 3
// 433.617 us; speedup vs baseline: 1.3129x; 1.3129x over previous
//
#include <hip/hip_runtime.h>
#include <hip/hip_fp16.h>

// Fern patch-descriptor pipeline, fully fused single kernel.
//   x:(64,8,128,128) f32, thresholds:(8,12) f32, table:(8,4096,32) f32,
//   chan_idx:(8,12,2) i32, offsets:(8,12,2,2) i32
//   out:(64, 32*114*114) f32
//
// R2: votes buffer in LDS stored as f16 (45 KB vs 90 KB f32) ->
// LDS = 34848 + 45000 = 79848 B -> 2 blocks/CU (20 waves/CU) for latency
// hiding of L2 table gathers + LDS reads. Phase 2 reverted to R0's
// per-fern interleaved structure (R1's decoupled-gather restructure
// regressed 404->514 us).

#define NN 64
#define CC 8
#define HH 128
#define WW 128
#define MM 8
#define KK 12
#define DD 32
#define OUTS 114
#define TT 19          // output tile edge (114 = 6*19 exact)
#define PT 25          // position tile edge = TT + POOL - 1
#define XT 33          // x tile edge = PT + L - 1
#define XSTRIDE (XT*XT)   // 1089
#define VSTRIDE 36        // vote row stride in halves (72 B rows, 8B-aligned)
#define NPOSI (PT*PT)     // 625
#define THREADS 640
#define POOLW 7

#define LDS_BYTES (CC*XSTRIDE*4 + NPOSI*VSTRIDE*2)   // 34848 + 45000 = 79848

// 8-byte LDS accessors: 4 halves <-> float4
__device__ __forceinline__ float4 ld4h(const __half* p) {
    union { float2 f; __half2 h[2]; } u;
    u.f = *(const float2*)p;
    float2 a = __half22float2(u.h[0]);
    float2 b = __half22float2(u.h[1]);
    return make_float4(a.x, a.y, b.x, b.y);
}
__device__ __forceinline__ void st4h(__half* p, float4 v) {
    union { float2 f; __half2 h[2]; } u;
    u.h[0] = __floats2half2_rn(v.x, v.y);
    u.h[1] = __floats2half2_rn(v.z, v.w);
    *(float2*)p = u.f;
}

__global__ __launch_bounds__(THREADS, 2)
void fern_fused(const float* __restrict__ x,
                const float* __restrict__ thresholds,
                const float* __restrict__ table,
                const int*   __restrict__ chan_idx,
                const int*   __restrict__ offsets,
                float* __restrict__ out)
{
    extern __shared__ float smem[];
    float*  xs = smem;                           // [8][33][33] f32
    __half* vs = (__half*)(smem + CC*XSTRIDE);   // [625][36] f16

    const int tile = blockIdx.x;         // 0..2303
    const int n    = tile / 36;
    const int t2   = tile - n*36;
    const int ti   = t2 / 6;
    const int tj   = t2 - ti*6;
    const int i0   = ti * TT;            // 0..95
    const int j0   = tj * TT;

    const int tid = threadIdx.x;

    // ---------------- Phase 1: stage x tile into LDS ----------------
    // rows i0..i0+32 <= 127, cols j0..j0+32 <= 127 exactly: no clamping.
    const float* xn = x + (size_t)n * (CC*HH*WW);
    for (int idx = tid; idx < CC*XSTRIDE; idx += THREADS) {
        int c   = idx / XSTRIDE;
        int rem = idx - c*XSTRIDE;
        int r   = rem / XT;
        int col = rem - r*XT;
        xs[idx] = xn[(c*HH + (i0 + r))*WW + (j0 + col)];
    }
    __syncthreads();

    // ---------------- Phase 2: per-position fern votes into LDS ------------
    // 625 positions, 640 threads: one balanced pass. R0 per-fern structure:
    // fern m's gather overlaps fern m+1's bit compute (compiler-scheduled).
    if (tid < NPOSI) {
        const int y  = tid / PT;
        const int j  = tid - y*PT;
        const int pb = y*XT + j;

        float vote[DD];
        #pragma unroll
        for (int d = 0; d < DD; ++d) vote[d] = 0.f;

        #pragma unroll
        for (int m = 0; m < MM; ++m) {
            unsigned word = 0u;
            float P = 1.f;                    // prod(1 + exp(-10|z|))
            #pragma unroll
            for (int k = 0; k < KK; ++k) {
                const int mk = m*KK + k;
                // compile-time mk -> wave-uniform scalar loads
                int c1  = chan_idx[mk*2 + 0];
                int c2  = chan_idx[mk*2 + 1];
                int dy1 = offsets[mk*4 + 0];
                int dx1 = offsets[mk*4 + 1];
                int dy2 = offsets[mk*4 + 2];
                int dx2 = offsets[mk*4 + 3];
                float thr = thresholds[mk];
                float p1 = xs[c1*XSTRIDE + dy1*XT + dx1 + pb];
                float p2 = xs[c2*XSTRIDE + dy2*XT + dx2 + pb];
                float z  = (p1 - p2) - thr;
                if (z > 0.f) word |= (1u << k);
                float e = __expf(-10.f * fabsf(z));
                P += P * e;                   // P *= (1+e), single v_fma
            }
            float cf = __builtin_amdgcn_rcpf(P);   // conf = 1/P
            const float4* t = (const float4*)(table + (((size_t)m << 12) + word)*DD);
            #pragma unroll
            for (int d4 = 0; d4 < DD/4; ++d4) {
                float4 tv = t[d4];
                vote[d4*4+0] += cf * tv.x;
                vote[d4*4+1] += cf * tv.y;
                vote[d4*4+2] += cf * tv.z;
                vote[d4*4+3] += cf * tv.w;
            }
        }

        __half* vrow = vs + tid*VSTRIDE;
        #pragma unroll
        for (int d4 = 0; d4 < DD/4; ++d4)
            st4h(vrow + d4*4, make_float4(vote[d4*4+0], vote[d4*4+1],
                                          vote[d4*4+2], vote[d4*4+3]));
    }
    __syncthreads();

    // ------------- Phase 3a: horizontal 7-window running sums (in-place) ----
    // work item = (y, d4): 25*8 = 200 items; each owns row (y,*,d4)
    for (int w = tid; w < PT*8; w += THREADS) {
        int y  = w / 8;
        int d4 = w - y*8;
        float4 s = make_float4(0.f, 0.f, 0.f, 0.f);
        float4 ring[POOLW];
        #pragma unroll
        for (int j = 0; j < PT; ++j) {
            float4 v = ld4h(vs + (y*PT + j)*VSTRIDE + d4*4);
            if (j >= POOLW) {
                float4 o = ring[j % POOLW];
                s.x -= o.x; s.y -= o.y; s.z -= o.z; s.w -= o.w;
            }
            ring[j % POOLW] = v;
            s.x += v.x; s.y += v.y; s.z += v.z; s.w += v.w;
            if (j >= POOLW-1) {
                // write index j-6 < j: already consumed, safe in-place
                st4h(vs + (y*PT + (j - POOLW + 1))*VSTRIDE + d4*4, s);
            }
        }
    }
    __syncthreads();

    // ---------------- Phase 3b: vertical 7-window + store -----------------
    // work item = (d4, jo) with jo fastest for store coalescing: 8*19 = 152
    const float inv = 1.f / 49.f;
    float* outn = out + (size_t)n * (DD*OUTS*OUTS);
    for (int w = tid; w < 8*TT; w += THREADS) {
        int d4 = w / TT;
        int jo = w - d4*TT;
        float4 s = make_float4(0.f, 0.f, 0.f, 0.f);
        float4 ring[POOLW];
        #pragma unroll
        for (int y = 0; y < PT; ++y) {
            float4 v = ld4h(vs + (y*PT + jo)*VSTRIDE + d4*4);
            if (y >= POOLW) {
                float4 o = ring[y % POOLW];
                s.x -= o.x; s.y -= o.y; s.z -= o.z; s.w -= o.w;
            }
            ring[y % POOLW] = v;
            s.x += v.x; s.y += v.y; s.z += v.z; s.w += v.w;
            if (y >= POOLW-1) {
                int io = y - POOLW + 1;
                size_t base = ((size_t)(d4*4)*OUTS + (i0 + io))*OUTS + (j0 + jo);
                outn[base                      ] = s.x * inv;
                outn[base +   (size_t)OUTS*OUTS] = s.y * inv;
                outn[base + 2*(size_t)OUTS*OUTS] = s.z * inv;
                outn[base + 3*(size_t)OUTS*OUTS] = s.w * inv;
            }
        }
    }
}

extern "C" void kernel_launch(void* const* d_in, const int* in_sizes, int n_in,
                              void* d_out, int out_size, void* d_ws, size_t ws_size,
                              hipStream_t stream) {
    const float* x          = (const float*)d_in[0];
    const float* thresholds = (const float*)d_in[1];
    const float* table      = (const float*)d_in[2];
    const int*   chan_idx   = (const int*)d_in[3];
    const int*   offsets    = (const int*)d_in[4];
    float* out = (float*)d_out;

    // dynamic LDS > 64KB needs the opt-in attribute (idempotent, capture-safe)
    hipFuncSetAttribute((const void*)fern_fused,
                        hipFuncAttributeMaxDynamicSharedMemorySize, LDS_BYTES);

    dim3 grid(NN * 36);
    dim3 block(THREADS);
    fern_fused<<<grid, block, LDS_BYTES, stream>>>(x, thresholds, table,
                                                   chan_idx, offsets, out);
}